// Round 3
// baseline (228.594 us; speedup 1.0000x reference)
//
#include <hip/hip_runtime.h>
#include <stdint.h>
#include <stddef.h>

// Problem constants
#define SEQ   512
#define HID   512
#define NHEAD 8
#define HD    64
#define NBATCH 16
#define NTOK  8192      // NBATCH*SEQ
#define MAXD  10

typedef __attribute__((ext_vector_type(8))) short short8;
typedef __attribute__((ext_vector_type(4))) float f32x4;

typedef __attribute__((address_space(3))) void        as3_void;
typedef const __attribute__((address_space(1))) void  as1_cvoid;

#define MFMA16(a,b,c) __builtin_amdgcn_mfma_f32_16x16x32_bf16((a),(b),(c),0,0,0)

__device__ __forceinline__ uint16_t f2bf(float f){
  uint32_t i = __float_as_uint(f);
  return (uint16_t)((i + 0x7fffu + ((i>>16)&1u)) >> 16);
}

enum { EPI_BF16=0, EPI_F32=3, EPI_RELU=4 };

// ---------------------------------------------------------------------------
// fp32 -> bf16 elementwise convert (x staging for the MFMA pipeline)
// ---------------------------------------------------------------------------
__global__ __launch_bounds__(256) void f2bf_kernel(
    const float* __restrict__ in, uint16_t* __restrict__ out, int n4)
{
  int i = blockIdx.x*256 + threadIdx.x;
  if (i < n4){
    float4 v = *(const float4*)(in + (size_t)i*4);
    *(ushort4*)(out + (size_t)i*4) =
        make_ushort4(f2bf(v.x), f2bf(v.y), f2bf(v.z), f2bf(v.w));
  }
}

// ---------------------------------------------------------------------------
// Weight transpose + fp32->bf16: W[R][C] f32 -> Wt[C][R] bf16, six matrices.
// ---------------------------------------------------------------------------
__global__ __launch_bounds__(256) void transpose_all(
    const float* __restrict__ Wq, const float* __restrict__ Wk,
    const float* __restrict__ Wv, const float* __restrict__ Wo,
    const float* __restrict__ W1, const float* __restrict__ W2,
    uint16_t* __restrict__ tq, uint16_t* __restrict__ tk,
    uint16_t* __restrict__ tv, uint16_t* __restrict__ to_,
    uint16_t* __restrict__ t1, uint16_t* __restrict__ t2)
{
  __shared__ uint16_t tile[32][33];
  int id = blockIdx.x;
  const float* in; uint16_t* out; int R, C, tx, ty;
  if (id < 1024) {
    int m = id >> 8, loc = id & 255;
    in  = (m==0)?Wq:(m==1)?Wk:(m==2)?Wv:Wo;
    out = (m==0)?tq:(m==1)?tk:(m==2)?tv:to_;
    R = 512; C = 512; ty = loc>>4; tx = loc&15;
  } else if (id < 2048) {
    int loc = id-1024; in=W1; out=t1; R=512; C=2048; ty=loc>>6; tx=loc&63;
  } else {
    int loc = id-2048; in=W2; out=t2; R=2048; C=512; ty=loc>>4; tx=loc&15;
  }
  int bx = tx*32, by = ty*32;
  int lx = threadIdx.x & 31, ly = threadIdx.x >> 5;   // 32x8
  #pragma unroll
  for (int i=ly; i<32; i+=8) tile[i][lx] = f2bf(in[(size_t)(by+i)*C + bx+lx]);
  __syncthreads();
  #pragma unroll
  for (int i=ly; i<32; i+=8) out[(size_t)(bx+i)*R + by+lx] = tile[lx][i];
}

// ---------------------------------------------------------------------------
// GEMM mainloop: C[128x128] = A[M,K] @ Bt[N,K]^T, bf16 in, f32 acc.
// m97 structure: 4 waves, 16x16x32 MFMA, global_load_lds width 16, 2 barriers.
// ---------------------------------------------------------------------------
__device__ __forceinline__ void gemm_tile_mainloop(
    const uint16_t* __restrict__ A, const uint16_t* __restrict__ Bt,
    int K, int m0, int n0, uint16_t* lA, uint16_t* lB, f32x4 acc[4][4])
{
  const int t = threadIdx.x;
  const int w = t>>6, l = t&63;
  const int lg = l>>4, lc = l&15;
  const int wr = w>>1, wc = w&1;
  const int kSteps = K>>6;
  for (int kt=0; kt<kSteps; ++kt){
    const int k0 = kt<<6;
    #pragma unroll
    for (int rd=0; rd<4; ++rd){
      const int e   = rd*2048 + t*8;        // element offset in 128x64 tile
      const int row = e>>6, col = e&63;
      const uint16_t* ga = A  + (size_t)(m0+row)*K + (k0+col);
      const uint16_t* gb = Bt + (size_t)(n0+row)*K + (k0+col);
      char* la = (char*)lA + rd*4096 + w*1024;   // wave-uniform dest base
      char* lb = (char*)lB + rd*4096 + w*1024;
      __builtin_amdgcn_global_load_lds((as1_cvoid*)ga, (as3_void*)la, 16, 0, 0);
      __builtin_amdgcn_global_load_lds((as1_cvoid*)gb, (as3_void*)lb, 16, 0, 0);
    }
    __syncthreads();   // drains vmcnt: LDS tiles ready
    #pragma unroll
    for (int kk=0; kk<2; ++kk){
      short8 af[4], bfr[4];
      #pragma unroll
      for (int i=0;i<4;i++){
        af[i]  = *(const short8*)&lA[(wr*64 + i*16 + lc)*64 + kk*32 + lg*8];
        bfr[i] = *(const short8*)&lB[(wc*64 + i*16 + lc)*64 + kk*32 + lg*8];
      }
      #pragma unroll
      for (int i=0;i<4;i++)
        #pragma unroll
        for (int j=0;j<4;j++)
          acc[i][j] = MFMA16(af[i], bfr[j], acc[i][j]);
    }
    __syncthreads();   // protect LDS before next stage
  }
}

// Generic GEMM with epilogue template (bias fp32).
//  EPI_BF16/RELU: bf16 [M][N];  EPI_F32: f32 [M][N]
template<int EPI>
__global__ __launch_bounds__(256,2) void gemm_bt(
    const uint16_t* __restrict__ A, const uint16_t* __restrict__ Bt,
    const float* __restrict__ bias, void* __restrict__ outp,
    int M, int N, int K)
{
  __shared__ uint16_t lA[128*64];
  __shared__ uint16_t lB[128*64];
  f32x4 acc[4][4];
  #pragma unroll
  for (int i=0;i<4;i++)
    #pragma unroll
    for (int j=0;j<4;j++){ f32x4 z = {0.f,0.f,0.f,0.f}; acc[i][j]=z; }
  const int m0 = blockIdx.y*128, n0 = blockIdx.x*128;
  gemm_tile_mainloop(A, Bt, K, m0, n0, lA, lB, acc);

  const int t=threadIdx.x, w=t>>6, l=t&63, lg=l>>4, lc=l&15, wr=w>>1, wc=w&1;
  #pragma unroll
  for (int j=0;j<4;j++){
    const int col = n0 + wc*64 + j*16 + lc;
    const float bs = bias[col];
    #pragma unroll
    for (int i=0;i<4;i++){
      const int rowb = m0 + wr*64 + i*16 + lg*4;
      #pragma unroll
      for (int r=0;r<4;r++){
        float v = acc[i][j][r] + bs;
        if constexpr (EPI==EPI_RELU)   v = fmaxf(v, 0.f);
        if constexpr (EPI==EPI_F32)
          ((float*)outp)[(size_t)(rowb+r)*N + col] = v;
        else
          ((uint16_t*)outp)[(size_t)(rowb+r)*N + col] = f2bf(v);
      }
    }
  }
}

// Fused QKV: grid.z selects {q(scaled), k(natural), v(transposed)}
__global__ __launch_bounds__(256,2) void qkv_gemm(
    const uint16_t* __restrict__ x,
    const uint16_t* __restrict__ wtq, const uint16_t* __restrict__ wtk,
    const uint16_t* __restrict__ wtv,
    const float* __restrict__ bq, const float* __restrict__ bk,
    const float* __restrict__ bv,
    uint16_t* __restrict__ qo, uint16_t* __restrict__ ko,
    uint16_t* __restrict__ vto)
{
  __shared__ uint16_t lA[128*64];
  __shared__ uint16_t lB[128*64];
  const int z = blockIdx.z;
  const uint16_t* Bt = (z==0)?wtq:(z==1)?wtk:wtv;
  const float*  bias = (z==0)?bq :(z==1)?bk :bv;
  f32x4 acc[4][4];
  #pragma unroll
  for (int i=0;i<4;i++)
    #pragma unroll
    for (int j=0;j<4;j++){ f32x4 zz = {0.f,0.f,0.f,0.f}; acc[i][j]=zz; }
  const int m0 = blockIdx.y*128, n0 = blockIdx.x*128;
  gemm_tile_mainloop(x, Bt, HID, m0, n0, lA, lB, acc);

  const int t=threadIdx.x, w=t>>6, l=t&63, lg=l>>4, lc=l&15, wr=w>>1, wc=w&1;
  if (z==2){
    #pragma unroll
    for (int j=0;j<4;j++){
      const int col = n0 + wc*64 + j*16 + lc;
      const float bs = bias[col];
      #pragma unroll
      for (int i=0;i<4;i++){
        const int rowb = m0 + wr*64 + i*16 + lg*4;
        *(ushort4*)(vto + (size_t)col*NTOK + rowb) =
            make_ushort4(f2bf(acc[i][j][0]+bs), f2bf(acc[i][j][1]+bs),
                         f2bf(acc[i][j][2]+bs), f2bf(acc[i][j][3]+bs));
      }
    }
  } else {
    uint16_t* o = (z==0) ? qo : ko;
    const float scale = (z==0) ? 0.125f : 1.0f;   // fold 1/sqrt(HD) into q
    #pragma unroll
    for (int j=0;j<4;j++){
      const int col = n0 + wc*64 + j*16 + lc;
      const float bs = bias[col];
      #pragma unroll
      for (int i=0;i<4;i++){
        const int rowb = m0 + wr*64 + i*16 + lg*4;
        #pragma unroll
        for (int r=0;r<4;r++)
          o[(size_t)(rowb+r)*HID + col] = f2bf((acc[i][j][r] + bs)*scale);
      }
    }
  }
}

// ---------------------------------------------------------------------------
// Flash attention with Graphormer biases.
// Block: 512 threads = 8 waves = 8 heads; one (b, 32-row i-tile) per block.
// Swapped QK^T (mfma(K,Q) -> S^T) so bias gathers are contiguous per lane.
// ---------------------------------------------------------------------------
__global__ __launch_bounds__(512) void attn_kernel(
    const uint16_t* __restrict__ q,    // [NTOK][HID] bf16, pre-scaled by 0.125
    const uint16_t* __restrict__ k,    // [NTOK][HID] bf16
    const uint16_t* __restrict__ vt,   // [HID][NTOK] bf16
    const int*      __restrict__ dist, // [16][512][512] i32
    const float*    __restrict__ edge, // [16][512][512] f32
    const int*      __restrict__ mask, // [16][512] i32 (bool normalized)
    const float*    __restrict__ semb, // [10][8] f32
    const float*    __restrict__ ew,   // [8]
    const float*    __restrict__ eb,   // [8]
    uint16_t* __restrict__ out)        // [NTOK][HID] bf16
{
  __shared__ float sp[MAXD*NHEAD];          // spatial_emb f32
  __shared__ uint16_t plds[NHEAD][32][72];  // P tile per head, +8 pad
  const int b  = blockIdx.y;
  const int i0 = blockIdx.x*32;
  const int t  = threadIdx.x;
  const int h  = t>>6, l = t&63, lg = l>>4, lc = l&15;
  if (t < MAXD*NHEAD) sp[t] = semb[t];
  __syncthreads();
  const float ewf = ew[h], ebf = eb[h];

  // Q fragments (B-operand of swapped QK^T)
  short8 qf[2][2];
  #pragma unroll
  for (int m=0;m<2;m++)
    #pragma unroll
    for (int kk=0;kk<2;kk++)
      qf[m][kk] = *(const short8*)&q[(size_t)(b*SEQ + i0 + m*16 + lc)*HID + h*HD + kk*32 + lg*8];

  float mrun[2] = {-1e30f, -1e30f};
  float lrun[2] = {0.f, 0.f};
  f32x4 oacc[2][4];
  #pragma unroll
  for (int m=0;m<2;m++)
    #pragma unroll
    for (int dn=0;dn<4;dn++){ f32x4 z={0.f,0.f,0.f,0.f}; oacc[m][dn]=z; }

  for (int jt=0; jt<8; ++jt){
    const int j0 = jt*64;
    // ---- S^T = K @ Q^T : st[jn][m], rows j, cols i -------------------------
    f32x4 st[4][2];
    #pragma unroll
    for (int jn=0;jn<4;jn++)
      #pragma unroll
      for (int m=0;m<2;m++){ f32x4 z={0.f,0.f,0.f,0.f}; st[jn][m]=z; }
    #pragma unroll
    for (int jn=0;jn<4;jn++){
      #pragma unroll
      for (int kk=0;kk<2;kk++){
        short8 kf = *(const short8*)&k[(size_t)(b*SEQ + j0 + jn*16 + lc)*HID + h*HD + kk*32 + lg*8];
        st[jn][0] = MFMA16(kf, qf[0][kk], st[jn][0]);
        st[jn][1] = MFMA16(kf, qf[1][kk], st[jn][1]);
      }
    }
    // ---- biases + mask; in-place into st; track tile max -------------------
    float tmax[2] = {-1e30f, -1e30f};
    #pragma unroll
    for (int jn=0;jn<4;jn++){
      const int jb = j0 + jn*16 + lg*4;
      int4 mk = *(const int4*)&mask[(size_t)b*SEQ + jb];
      const int mka[4] = {mk.x, mk.y, mk.z, mk.w};
      #pragma unroll
      for (int m=0;m<2;m++){
        const int gi = i0 + m*16 + lc;
        const size_t base = ((size_t)b*SEQ + gi)*SEQ + jb;
        int4   d4 = *(const int4*)&dist[base];
        float4 e4 = *(const float4*)&edge[base];
        const int   da[4] = {d4.x, d4.y, d4.z, d4.w};
        const float ea[4] = {e4.x, e4.y, e4.z, e4.w};
        #pragma unroll
        for (int r=0;r<4;r++){
          float sv = mka[r] ? -1e30f
                            : st[jn][m][r] + sp[da[r]*NHEAD + h] + ea[r]*ewf + ebf;
          st[jn][m][r] = sv;
          tmax[m] = fmaxf(tmax[m], sv);
        }
      }
    }
    // ---- online softmax per i (i = m*16+lc is lane-local in S^T) -----------
    #pragma unroll
    for (int m=0;m<2;m++){
      float tm = fmaxf(tmax[m], __shfl_xor(tmax[m], 16, 64));
      tm = fmaxf(tm, __shfl_xor(tm, 32, 64));
      float mnew = fmaxf(mrun[m], tm);
      mnew = fmaxf(mnew, -1e20f);           // guard: fully-masked tile
      const float c = __expf(mrun[m] - mnew);
      mrun[m] = mnew;
      float lsum = 0.f;
      #pragma unroll
      for (int jn=0;jn<4;jn++){
        float p0 = __expf(st[jn][m][0]-mnew);
        float p1 = __expf(st[jn][m][1]-mnew);
        float p2 = __expf(st[jn][m][2]-mnew);
        float p3 = __expf(st[jn][m][3]-mnew);
        lsum += (p0+p1)+(p2+p3);
        *(ushort4*)&plds[h][m*16+lc][jn*16+lg*4] =
            make_ushort4(f2bf(p0), f2bf(p1), f2bf(p2), f2bf(p3));
      }
      lrun[m] = lrun[m]*c + lsum;
      #pragma unroll
      for (int r=0;r<4;r++){
        const float cr = __shfl(c, lg*4+r, 64);
        #pragma unroll
        for (int dn=0;dn<4;dn++) oacc[m][dn][r] *= cr;
      }
    }
    // ---- PV: O += P @ V  (V read from transposed layout) -------------------
    #pragma unroll
    for (int kk=0;kk<2;kk++){
      short8 pa0 = *(const short8*)&plds[h][lc]   [kk*32 + lg*8];
      short8 pa1 = *(const short8*)&plds[h][16+lc][kk*32 + lg*8];
      #pragma unroll
      for (int dn=0;dn<4;dn++){
        short8 vb = *(const short8*)&vt[(size_t)(h*HD + dn*16 + lc)*NTOK
                                        + (size_t)b*SEQ + j0 + kk*32 + lg*8];
        oacc[0][dn] = MFMA16(pa0, vb, oacc[0][dn]);
        oacc[1][dn] = MFMA16(pa1, vb, oacc[1][dn]);
      }
    }
  }
  // ---- finalize: divide by row sum, store bf16 -----------------------------
  #pragma unroll
  for (int m=0;m<2;m++){
    float ls = lrun[m];
    ls += __shfl_xor(ls, 16, 64);
    ls += __shfl_xor(ls, 32, 64);
    const float inv = 1.f/ls;
    #pragma unroll
    for (int r=0;r<4;r++){
      const float ir = __shfl(inv, lg*4+r, 64);
      const size_t orow = ((size_t)b*SEQ + i0 + m*16 + lg*4 + r)*HID;
      #pragma unroll
      for (int dn=0;dn<4;dn++)
        out[orow + h*HD + dn*16 + lc] = f2bf(oacc[m][dn][r]*ir);
    }
  }
}

// ---------------------------------------------------------------------------
// LayerNorm with fused residual: u = a + b (both f32); LN(u) -> f32 + opt bf16
// One wave per 512-wide row.
// ---------------------------------------------------------------------------
__global__ __launch_bounds__(256) void ln_kernel(
    const float* __restrict__ a, const float* __restrict__ bsrc,
    const float* __restrict__ g, const float* __restrict__ bb,
    float* __restrict__ of, uint16_t* __restrict__ ob)
{
  const int row = blockIdx.x*4 + (threadIdx.x>>6);
  const int l = threadIdx.x & 63;
  const float* ar = a    + (size_t)row*HID;
  const float* br = bsrc + (size_t)row*HID;
  float u[8];
  {
    float4 a0 = *(const float4*)(ar + l*4);
    float4 a1 = *(const float4*)(ar + 256 + l*4);
    float4 b0 = *(const float4*)(br + l*4);
    float4 b1 = *(const float4*)(br + 256 + l*4);
    u[0]=a0.x+b0.x; u[1]=a0.y+b0.y; u[2]=a0.z+b0.z; u[3]=a0.w+b0.w;
    u[4]=a1.x+b1.x; u[5]=a1.y+b1.y; u[6]=a1.z+b1.z; u[7]=a1.w+b1.w;
  }
  float s=0.f, ss=0.f;
  #pragma unroll
  for (int e=0;e<8;e++){ s += u[e]; ss += u[e]*u[e]; }
  #pragma unroll
  for (int off=32; off>=1; off>>=1){
    s  += __shfl_xor(s,  off, 64);
    ss += __shfl_xor(ss, off, 64);
  }
  const float mu  = s*(1.f/512.f);
  const float inv = rsqrtf(ss*(1.f/512.f) - mu*mu + 1e-5f);
  float y[8];
  #pragma unroll
  for (int e=0;e<4;e++){
    int c0 = l*4+e, c1 = 256+l*4+e;
    y[e]   = (u[e]  -mu)*inv*g[c0] + bb[c0];
    y[4+e] = (u[4+e]-mu)*inv*g[c1] + bb[c1];
  }
  if (of){
    float* orow = of + (size_t)row*HID;
    *(float4*)(orow + l*4)       = make_float4(y[0],y[1],y[2],y[3]);
    *(float4*)(orow + 256 + l*4) = make_float4(y[4],y[5],y[6],y[7]);
  }
  if (ob){
    uint16_t* brow = ob + (size_t)row*HID;
    *(ushort4*)(brow + l*4)       = make_ushort4(f2bf(y[0]),f2bf(y[1]),f2bf(y[2]),f2bf(y[3]));
    *(ushort4*)(brow + 256 + l*4) = make_ushort4(f2bf(y[4]),f2bf(y[5]),f2bf(y[6]),f2bf(y[7]));
  }
}

// ---------------------------------------------------------------------------
extern "C" void kernel_launch(void* const* d_in, const int* in_sizes, int n_in,
                              void* d_out, int out_size, void* d_ws, size_t ws_size,
                              hipStream_t stream)
{
  (void)in_sizes; (void)n_in; (void)out_size; (void)ws_size;
  const float* x    = (const float*)d_in[0];
  const int*   dist = (const int*)  d_in[1];
  const float* edge = (const float*)d_in[2];
  const int*   mask = (const int*)  d_in[3];
  const float* Wq = (const float*)d_in[4];
  const float* bq = (const float*)d_in[5];
  const float* Wk = (const float*)d_in[6];
  const float* bk = (const float*)d_in[7];
  const float* Wv = (const float*)d_in[8];
  const float* bv = (const float*)d_in[9];
  const float* Wo = (const float*)d_in[10];
  const float* bo = (const float*)d_in[11];
  const float* semb = (const float*)d_in[12];
  const float* ew   = (const float*)d_in[13];
  const float* eb   = (const float*)d_in[14];
  const float* ln1g = (const float*)d_in[15];
  const float* ln1b = (const float*)d_in[16];
  const float* ln2g = (const float*)d_in[17];
  const float* ln2b = (const float*)d_in[18];
  const float* W1 = (const float*)d_in[19];
  const float* b1 = (const float*)d_in[20];
  const float* W2 = (const float*)d_in[21];
  const float* b2 = (const float*)d_in[22];

  // workspace layout (~90.2 MB)
  char* ws = (char*)d_ws;
  uint16_t* xb16  = (uint16_t*)ws;                        // [NTOK][HID] bf16
  uint16_t* qbuf  = xb16  + (size_t)NTOK*HID;
  uint16_t* kbuf  = qbuf  + (size_t)NTOK*HID;
  uint16_t* vtbuf = kbuf  + (size_t)NTOK*HID;             // [HID][NTOK]
  uint16_t* aobuf = vtbuf + (size_t)NTOK*HID;
  uint16_t* f1buf = qbuf;                                 // aliases q/k/vt/ao (33.5 MB)
  float*    tbuf  = (float*)(ws + (size_t)5*NTOK*HID*2);  // f32, 16.78 MB
  float*    t2buf = tbuf;                                 // alias (t dead after LN1)
  float*    hbuf  = tbuf + (size_t)NTOK*HID;              // f32, 16.78 MB
  uint16_t* hb16  = (uint16_t*)(hbuf + (size_t)NTOK*HID); // bf16, 8.39 MB
  uint16_t* wt    = hb16 + (size_t)NTOK*HID;
  uint16_t* wtq = wt;
  uint16_t* wtk = wtq + 512*512;
  uint16_t* wtv = wtk + 512*512;
  uint16_t* wto = wtv + 512*512;
  uint16_t* wt1 = wto + 512*512;      // [2048][512]
  uint16_t* wt2 = wt1 + 512*2048;     // [512][2048]

  transpose_all<<<3072, 256, 0, stream>>>(Wq,Wk,Wv,Wo,W1,W2, wtq,wtk,wtv,wto,wt1,wt2);

  f2bf_kernel<<<4096, 256, 0, stream>>>(x, xb16, NTOK*HID/4);

  qkv_gemm<<<dim3(4,64,3), 256, 0, stream>>>(xb16, wtq,wtk,wtv, bq,bk,bv,
                                             qbuf,kbuf,vtbuf);

  attn_kernel<<<dim3(16,16), 512, 0, stream>>>(qbuf,kbuf,vtbuf, dist, edge, mask,
                                               semb, ew, eb, aobuf);

  gemm_bt<EPI_F32><<<dim3(4,64), 256, 0, stream>>>(aobuf, wto, bo, tbuf, NTOK, HID, HID);

  ln_kernel<<<2048, 256, 0, stream>>>(tbuf, x, ln1g, ln1b, hbuf, hb16);

  gemm_bt<EPI_RELU><<<dim3(16,64), 256, 0, stream>>>(hb16, wt1, b1, f1buf, NTOK, 2048, HID);

  gemm_bt<EPI_F32><<<dim3(4,64), 256, 0, stream>>>(f1buf, wt2, b2, t2buf, NTOK, HID, 2048);

  ln_kernel<<<2048, 256, 0, stream>>>(t2buf, hbuf, ln2g, ln2b, (float*)d_out, nullptr);
}